// Round 12
// baseline (103.926 us; speedup 1.0000x reference)
//
#include <hip/hip_runtime.h>
#include <hip/hip_fp8.h>
#include <math.h>

#define N 8192
#define D 512
#define TT 64              // 8192/128 tiles per side
#define NT 2080            // TT*(TT+1)/2
#define NEG_INF_SENT (-3.0e38f)
#define SCALE1 0x7F7F7F7F   // E8M0 = 127 -> 2^0 = 1.0 in all four bytes

typedef __attribute__((ext_vector_type(8))) int int8x;      // 32 fp8 in 8 VGPRs
typedef __attribute__((ext_vector_type(16))) float f32x16;  // 32x32 C/D frag

#define AS1 __attribute__((address_space(1)))
#define AS3 __attribute__((address_space(3)))

__device__ inline void lse_merge(float& m1, float& s1, float m2, float s2) {
    float M = fmaxf(m1, m2);
    s1 = s1 * __expf(m1 - M) + s2 * __expf(m2 - M);
    m1 = M;
}

// ---- fused cast(fp32->fp8 e4m3, fragment-swizzled layout) + row-sumsq --------
// xb layout: 32-row group g, K-chunk c (64 k), half h (16-B k-seg):
//   1-KB unit at ((g*8+c)*2+h)<<10, interior offset (seg32*32 + row&31)*16
// = exactly the lane-order image the 32x32x64 MFMA operand wants
// (lane l: row l&31, k=(l>>5)*32 + h*16 + [0,16)).
__global__ __launch_bounds__(256) void cast_rowsq_kernel(const float* __restrict__ x,
                                                         unsigned char* __restrict__ xb,
                                                         float* __restrict__ sq) {
#pragma unroll
    for (int g4 = 0; g4 < 4; ++g4) {
        int row = blockIdx.x * 16 + g4 * 4 + (threadIdx.x >> 6);
        int lane = threadIdx.x & 63;
        const float4* xr = (const float4*)(x + (size_t)row * D);
        float4 a = xr[lane * 2], b = xr[lane * 2 + 1];
        float v[8] = {a.x, a.y, a.z, a.w, b.x, b.y, b.z, b.w};
        float s = 0.f;
        unsigned int byt[8];
#pragma unroll
        for (int e = 0; e < 8; ++e) {
            s += v[e] * v[e];
            __hip_fp8_e4m3 f8(v[e]);            // OCP e4m3fn
            byt[e] = (unsigned int)f8.__x;
        }
        uint2 pk;
        pk.x = byt[0] | (byt[1] << 8) | (byt[2] << 16) | (byt[3] << 24);
        pk.y = byt[4] | (byt[5] << 8) | (byt[6] << 16) | (byt[7] << 24);
        int g = row >> 5, rl = row & 31;
        int c = lane >> 3;                 // K-chunk (64)
        int l5 = (lane >> 2) & 1;          // 32-k segment within chunk
        int h = (lane >> 1) & 1;           // 16-B half within segment
        int bb = (lane & 1) << 3;          // byte within 16-B unit
        size_t addr = ((size_t)((g * 8 + c) * 2 + h) << 10) + ((l5 * 32 + rl) << 4) + bb;
        *(uint2*)(xb + addr) = pk;
#pragma unroll
        for (int off = 32; off > 0; off >>= 1) s += __shfl_down(s, off, 64);
        if (lane == 0) sq[row] = s;
    }
}

// ---- MX-fp8 MFMA pair kernel: 128x128 tile, K-chunk 128, 2 blocks/CU ---------
// 4 waves, wave-tile 64x64 = 2x2 frags of 32x32x64 (acc 64 AGPR). LDS dbuf
// 2x32KB -> 64KB/block -> 2 blocks/CU; independent barriers overlap drains.
// Staging: per chunk 32 dense 1-KB DMAs (8/wave), per-lane gptr = base+lane*16
// (r11's wave-uniform-gptr bug fixed). Grid 2080: tail loss only 1.5%.
// C/D layout (m74/m101): col=lane&31, row=(reg&3)+8*(reg>>2)+4*(lane>>5).
__global__ __launch_bounds__(256, 2) void pair_mfma_kernel(const unsigned char* __restrict__ xb,
                                                           const float* __restrict__ sq,
                                                           float* __restrict__ bm,
                                                           float* __restrict__ bs) {
    // unit f = side*16 + g*4 + cc*2 + h  (side: 0=A,1=B; g: 32-row group;
    // cc: 64-k within the 128-k chunk; h: 16-B half of 32-k segment)
    __shared__ __align__(16) unsigned char lds[2][32][1024];   // 64 KB

    const int p = blockIdx.x;
    const int b = (p & 7) * 260 + (p >> 3);          // XCD-contiguous runs (2080 = 8*260)
    int bi = 0;
    while ((bi + 1) * (2 * TT - bi) / 2 <= b) ++bi;
    const int bj = bi + (b - bi * (2 * TT - bi + 1) / 2);
    const int i0 = bi * 128, j0 = bj * 128;
    const int gA = i0 >> 5, gB = j0 >> 5;

    const int tid = threadIdx.x;
    const int lane = tid & 63;
    const int w = tid >> 6;          // 0..3
    const int wy = w >> 1, wx = w & 1;
    const int l31 = lane & 31;
    const int l5 = lane >> 5;

    f32x16 acc[2][2];
#pragma unroll
    for (int mi = 0; mi < 2; ++mi)
#pragma unroll
        for (int ni = 0; ni < 2; ++ni)
#pragma unroll
            for (int r = 0; r < 16; ++r) acc[mi][ni][r] = 0.f;

    // stage one 128-k chunk C into buf: this wave's 8 of the 32 1-KB units
    auto stage = [&](int C, int buf) {
#pragma unroll
        for (int u = 0; u < 8; ++u) {
            int f = (w << 3) | u;
            int side = f >> 4;
            int g = (f >> 2) & 3;
            int cc = (f >> 1) & 1;
            int h = f & 1;
            int grp = (side ? gB : gA) + g;
            int cg = C * 2 + cc;
            const unsigned char* src = xb + (((size_t)((grp * 8 + cg) * 2 + h)) << 10)
                                          + (lane << 4);   // per-lane: dense 1 KB
            __builtin_amdgcn_global_load_lds((const AS1 void*)src,
                                             (AS3 void*)&lds[buf][f][0], 16, 0, 0);
        }
    };

    stage(0, 0);
    __syncthreads();

    for (int C = 0; C < 4; ++C) {
        const int cur = C & 1;
        if (C < 3) stage(C + 1, cur ^ 1);
#pragma unroll
        for (int cc = 0; cc < 2; ++cc) {
            int8x af[2], bf[2];
#pragma unroll
            for (int mi = 0; mi < 2; ++mi) {
                int f = ((wy * 2 + mi) << 2) | (cc << 1);          // side 0
                uint4 lo = *(const uint4*)&lds[cur][f][lane << 4];
                uint4 hi = *(const uint4*)&lds[cur][f + 1][lane << 4];
                af[mi][0] = lo.x; af[mi][1] = lo.y; af[mi][2] = lo.z; af[mi][3] = lo.w;
                af[mi][4] = hi.x; af[mi][5] = hi.y; af[mi][6] = hi.z; af[mi][7] = hi.w;
            }
#pragma unroll
            for (int ni = 0; ni < 2; ++ni) {
                int f = 16 | ((wx * 2 + ni) << 2) | (cc << 1);     // side 1
                uint4 lo = *(const uint4*)&lds[cur][f][lane << 4];
                uint4 hi = *(const uint4*)&lds[cur][f + 1][lane << 4];
                bf[ni][0] = lo.x; bf[ni][1] = lo.y; bf[ni][2] = lo.z; bf[ni][3] = lo.w;
                bf[ni][4] = hi.x; bf[ni][5] = hi.y; bf[ni][6] = hi.z; bf[ni][7] = hi.w;
            }
#pragma unroll
            for (int mi = 0; mi < 2; ++mi)
#pragma unroll
                for (int ni = 0; ni < 2; ++ni)
                    acc[mi][ni] = __builtin_amdgcn_mfma_scale_f32_32x32x64_f8f6f4(
                        af[mi], bf[ni], acc[mi][ni], 0, 0, 0, SCALE1, 0, SCALE1);
        }
        __syncthreads();
    }

    // ---- branch-free epilogue ------------------------------------------------
    const bool offdiag = (bi != bj);
    float sqj[2];
#pragma unroll
    for (int ni = 0; ni < 2; ++ni) sqj[ni] = sq[j0 + wx * 64 + ni * 32 + l31];

    float m = NEG_INF_SENT;
#pragma unroll
    for (int mi = 0; mi < 2; ++mi) {
#pragma unroll
        for (int r = 0; r < 16; ++r) {
            int row32 = (r & 3) + 8 * (r >> 2) + 4 * l5;
            int i = i0 + wy * 64 + mi * 32 + row32;
            float sqi = sq[i];
#pragma unroll
            for (int ni = 0; ni < 2; ++ni) {
                int j = j0 + wx * 64 + ni * 32 + l31;
                float d2 = fmaxf(sqi + sqj[ni] - 2.f * acc[mi][ni][r], 0.f);
                float tv = (offdiag || j > i) ? (-2.0f * d2) : NEG_INF_SENT;
                acc[mi][ni][r] = tv;
                m = fmaxf(m, tv);
            }
        }
    }
    float s = 0.f;
#pragma unroll
    for (int mi = 0; mi < 2; ++mi)
#pragma unroll
        for (int ni = 0; ni < 2; ++ni)
#pragma unroll
            for (int r = 0; r < 16; ++r)
                s += __expf(acc[mi][ni][r] - m);

#pragma unroll
    for (int off = 32; off > 0; off >>= 1) {
        float m2 = __shfl_down(m, off, 64);
        float s2 = __shfl_down(s, off, 64);
        lse_merge(m, s, m2, s2);
    }
    __shared__ float rm[4], rs[4];
    if (lane == 0) { rm[w] = m; rs[w] = s; }
    __syncthreads();
    if (tid == 0) {
#pragma unroll
        for (int v = 1; v < 4; ++v) lse_merge(rm[0], rs[0], rm[v], rs[v]);
        bm[p] = rm[0];
        bs[p] = rs[0];
    }
}

__global__ __launch_bounds__(256) void finalize_kernel(const float* __restrict__ bm,
                                                       const float* __restrict__ bs,
                                                       int nblocks,
                                                       float* __restrict__ out) {
    const int tid = threadIdx.x;
    float m = NEG_INF_SENT, s = 0.f;
    for (int b = tid; b < nblocks; b += 256) lse_merge(m, s, bm[b], bs[b]);
#pragma unroll
    for (int off = 32; off > 0; off >>= 1) {
        float m2 = __shfl_down(m, off, 64);
        float s2 = __shfl_down(s, off, 64);
        lse_merge(m, s, m2, s2);
    }
    __shared__ float rm[4], rs[4];
    if ((tid & 63) == 0) { rm[tid >> 6] = m; rs[tid >> 6] = s; }
    __syncthreads();
    if (tid == 0) {
#pragma unroll
        for (int v = 1; v < 4; ++v) lse_merge(rm[0], rs[0], rm[v], rs[v]);
        const float log_num_pairs = 17.3285362f;  // log(8192*8191/2)
        out[0] = rm[0] + logf(rs[0]) - log_num_pairs;
    }
}

extern "C" void kernel_launch(void* const* d_in, const int* in_sizes, int n_in,
                              void* d_out, int out_size, void* d_ws, size_t ws_size,
                              hipStream_t stream) {
    const float* x = (const float*)d_in[0];
    float* out = (float*)d_out;

    const size_t xb_bytes = (size_t)N * D;    // 4 MB fp8 (swizzled)
    unsigned char* xb = (unsigned char*)d_ws;
    float* sq = (float*)((char*)d_ws + xb_bytes);
    float* bm = sq + N;
    float* bs = bm + NT;

    cast_rowsq_kernel<<<N / 16, 256, 0, stream>>>(x, xb, sq);
    pair_mfma_kernel<<<NT, 256, 0, stream>>>(xb, sq, bm, bs);
    finalize_kernel<<<1, 256, 0, stream>>>(bm, bs, NT, out);
}